// Round 1
// baseline (124.874 us; speedup 1.0000x reference)
//
#include <hip/hip_runtime.h>
#include <cmath>

// Problem constants (match reference)
#define BB 4
#define NN 48
#define TT 33
#define RR 16
#define NC 80
#define NI 5

// ---------------------------------------------------------------------------
// Kernel 1: per-(b,c) tropical chain DP.
//   H_l[x,y] = trans[b,x,y,rules[c,l]]   (l = 0,1,2), staged in LDS
//   S1 = H0 (x) H1   (max-plus matmul)
//   S  = S1 (x) H2
//   sw[b,c,x,y] = exp(S[x,y]) * weights[c]
// One 256-thread block per (b,c); each thread computes 9 outputs per product.
// ---------------------------------------------------------------------------
__global__ __launch_bounds__(256) void chain_dp_kernel(
    const float* __restrict__ trans,    // [B,N,N,T]
    const int*   __restrict__ rules,    // [Nc,3]
    const float* __restrict__ weights,  // [Nc] (= [Nt,Ni] flattened)
    float*       __restrict__ sw)       // [B,Nc,N,N]
{
    __shared__ float H0[NN * NN];
    __shared__ float H1[NN * NN];
    __shared__ float H2[NN * NN];
    __shared__ float S1[NN * NN];

    const int bc = blockIdx.x;
    const int b  = bc / NC;
    const int c  = bc - b * NC;

    const int r0 = rules[c * 3 + 0];
    const int r1 = rules[c * 3 + 1];
    const int r2 = rules[c * 3 + 2];
    const float w = weights[c];

    const float* tb = trans + (size_t)b * NN * NN * TT;

    // Gather hop matrices (stride-T reads; L2-resident, tiny)
    for (int i = threadIdx.x; i < NN * NN; i += 256) {
        const size_t base = (size_t)i * TT;
        H0[i] = tb[base + r0];
        H1[i] = tb[base + r1];
        H2[i] = tb[base + r2];
    }
    __syncthreads();

    // S1 = H0 (x) H1
    for (int i = threadIdx.x; i < NN * NN; i += 256) {
        const int x = i / NN;
        const int y = i - x * NN;
        const float* a = &H0[x * NN];
        float m = -INFINITY;
        #pragma unroll 8
        for (int k = 0; k < NN; ++k)
            m = fmaxf(m, a[k] + H1[k * NN + y]);
        S1[i] = m;
    }
    __syncthreads();

    // S = S1 (x) H2 ; fold exp and per-chain weight
    float* outp = sw + (size_t)bc * NN * NN;
    for (int i = threadIdx.x; i < NN * NN; i += 256) {
        const int x = i / NN;
        const int y = i - x * NN;
        const float* a = &S1[x * NN];
        float m = -INFINITY;
        #pragma unroll 8
        for (int k = 0; k < NN; ++k)
            m = fmaxf(m, a[k] + H2[k * NN + y]);
        outp[i] = __expf(m) * w;
    }
}

// ---------------------------------------------------------------------------
// Kernel 2: combine 5 weighted-exp chain planes per triple, add bias, mask.
//   out[b,x,y,t] = (type_mask[b,x,y,t]==0) ? sum_i sw[b,t*5+i,x,y] + bias[t]
//                                          : -1000
// ---------------------------------------------------------------------------
__global__ __launch_bounds__(256) void combine_kernel(
    const float* __restrict__ sw,      // [B,Nc,N,N]
    const int*   __restrict__ mask,    // [B,N,N,R]
    const float* __restrict__ biases,  // [R]
    float*       __restrict__ out)     // [B,N,N,R]
{
    const int idx = blockIdx.x * 256 + threadIdx.x;
    if (idx >= BB * NN * NN * RR) return;

    const int t  = idx & (RR - 1);
    const int bp = idx >> 4;            // b*N*N + p
    const int b  = bp / (NN * NN);
    const int p  = bp - b * (NN * NN);

    const float* base = sw + ((size_t)(b * NC + t * NI)) * NN * NN + p;
    float acc = biases[t];
    #pragma unroll
    for (int i = 0; i < NI; ++i)
        acc += base[(size_t)i * NN * NN];

    out[idx] = (mask[idx] == 0) ? acc : -1000.0f;
}

extern "C" void kernel_launch(void* const* d_in, const int* in_sizes, int n_in,
                              void* d_out, int out_size, void* d_ws, size_t ws_size,
                              hipStream_t stream)
{
    const float* trans   = (const float*)d_in[0];  // [B,N,N,T] f32
    const int*   mask    = (const int*)  d_in[1];  // [B,N,N,R] i32
    const int*   rules   = (const int*)  d_in[2];  // [Nc,3]    i32
    const float* weights = (const float*)d_in[3];  // [Nt,Ni]   f32
    const float* biases  = (const float*)d_in[4];  // [Nt]      f32
    float* out = (float*)d_out;
    float* sw  = (float*)d_ws;                     // [B,Nc,N,N] = 2.95 MB

    chain_dp_kernel<<<BB * NC, 256, 0, stream>>>(trans, rules, weights, sw);

    const int total = BB * NN * NN * RR;
    combine_kernel<<<(total + 255) / 256, 256, 0, stream>>>(sw, mask, biases, out);
}

// Round 2
// 75.470 us; speedup vs baseline: 1.6546x; 1.6546x over previous
//
#include <hip/hip_runtime.h>
#include <cmath>

// Problem constants (match reference)
#define BB 4
#define NN 48
#define NP 49   // padded row stride for transposed LDS tiles (conflict-free)
#define TT 33
#define RR 16
#define NC 80
#define NI 5

// ---------------------------------------------------------------------------
// Kernel 1: per-(b,c) tropical chain DP, register-tiled.
//   H0T[k][x] = trans[b,x,k,r0]  (transposed, padded stride 49)
//   H1[k][y]  = trans[b,k,y,r1]
//   H2[k][y]  = trans[b,k,y,r2]
//   S1 = H0 (x) H1  (max-plus), S = S1 (x) H2
//   sw[b,c,x,y] = exp(S[x,y]) * weights[c]
// 192 threads = 16 x-tiles (3 wide) x 12 y-tiles (4 wide); each thread owns a
// 3x4 output tile -> 12 independent accumulator chains, 4 LDS reads / 12 MACs.
// ---------------------------------------------------------------------------
__global__ __launch_bounds__(192) void chain_dp_kernel(
    const float* __restrict__ trans,    // [B,N,N,T]
    const int*   __restrict__ rules,    // [Nc,3]
    const float* __restrict__ weights,  // [Nc]
    float*       __restrict__ sw)       // [B,Nc,N,N]
{
    __shared__ float H0T[NN * NP];  // A of product 1, transposed [k][x]
    __shared__ float H1 [NN * NN];  // B of product 1, [k][y]
    __shared__ float H2 [NN * NN];  // B of product 2, [k][y]
    __shared__ float S1T[NN * NP];  // A of product 2, transposed [k][x]

    const int bc = blockIdx.x;
    const int b  = bc / NC;
    const int c  = bc - b * NC;

    const int r0 = rules[c * 3 + 0];
    const int r1 = rules[c * 3 + 1];
    const int r2 = rules[c * 3 + 2];
    const float w = weights[c];

    const float* tb = trans + (size_t)b * NN * NN * TT;

    // Gather hop matrices. H0T write addr = k*49 + x: lanes step k by 1 ->
    // address stride 49, gcd(49,32)=1 -> conflict-free.
    for (int i = threadIdx.x; i < NN * NN; i += 192) {
        const int x = i / NN;
        const int k = i - x * NN;
        const size_t base = (size_t)i * TT;
        H0T[k * NP + x] = tb[base + r0];
        H1[i]           = tb[base + r1];
        H2[i]           = tb[base + r2];
    }
    __syncthreads();

    const int tx = threadIdx.x & 15;   // 16 x-tiles
    const int ty = threadIdx.x >> 4;   // 12 y-tiles
    const int x0 = tx * 3;
    const int y0 = ty * 4;

    // ---- product 1: S1 = H0 (x) H1 ----
    float acc[3][4];
    #pragma unroll
    for (int jx = 0; jx < 3; ++jx)
        #pragma unroll
        for (int jy = 0; jy < 4; ++jy) acc[jx][jy] = -INFINITY;

    #pragma unroll 4
    for (int k = 0; k < NN; ++k) {
        const float a0 = H0T[k * NP + x0 + 0];
        const float a1 = H0T[k * NP + x0 + 1];
        const float a2 = H0T[k * NP + x0 + 2];
        const float4 bv = *(const float4*)&H1[k * NN + y0];
        acc[0][0] = fmaxf(acc[0][0], a0 + bv.x);
        acc[0][1] = fmaxf(acc[0][1], a0 + bv.y);
        acc[0][2] = fmaxf(acc[0][2], a0 + bv.z);
        acc[0][3] = fmaxf(acc[0][3], a0 + bv.w);
        acc[1][0] = fmaxf(acc[1][0], a1 + bv.x);
        acc[1][1] = fmaxf(acc[1][1], a1 + bv.y);
        acc[1][2] = fmaxf(acc[1][2], a1 + bv.z);
        acc[1][3] = fmaxf(acc[1][3], a1 + bv.w);
        acc[2][0] = fmaxf(acc[2][0], a2 + bv.x);
        acc[2][1] = fmaxf(acc[2][1], a2 + bv.y);
        acc[2][2] = fmaxf(acc[2][2], a2 + bv.z);
        acc[2][3] = fmaxf(acc[2][3], a2 + bv.w);
    }

    // S1T[y][x] write addr = (y0+jy)*49 + x0+jx: lanes step tx -> stride 3,
    // gcd(3,32)=1 -> conflict-free.
    #pragma unroll
    for (int jx = 0; jx < 3; ++jx)
        #pragma unroll
        for (int jy = 0; jy < 4; ++jy)
            S1T[(y0 + jy) * NP + x0 + jx] = acc[jx][jy];
    __syncthreads();

    // ---- product 2: S = S1 (x) H2, fused exp*weight epilogue ----
    float acc2[3][4];
    #pragma unroll
    for (int jx = 0; jx < 3; ++jx)
        #pragma unroll
        for (int jy = 0; jy < 4; ++jy) acc2[jx][jy] = -INFINITY;

    #pragma unroll 4
    for (int k = 0; k < NN; ++k) {
        const float a0 = S1T[k * NP + x0 + 0];
        const float a1 = S1T[k * NP + x0 + 1];
        const float a2 = S1T[k * NP + x0 + 2];
        const float4 bv = *(const float4*)&H2[k * NN + y0];
        acc2[0][0] = fmaxf(acc2[0][0], a0 + bv.x);
        acc2[0][1] = fmaxf(acc2[0][1], a0 + bv.y);
        acc2[0][2] = fmaxf(acc2[0][2], a0 + bv.z);
        acc2[0][3] = fmaxf(acc2[0][3], a0 + bv.w);
        acc2[1][0] = fmaxf(acc2[1][0], a1 + bv.x);
        acc2[1][1] = fmaxf(acc2[1][1], a1 + bv.y);
        acc2[1][2] = fmaxf(acc2[1][2], a1 + bv.z);
        acc2[1][3] = fmaxf(acc2[1][3], a1 + bv.w);
        acc2[2][0] = fmaxf(acc2[2][0], a2 + bv.x);
        acc2[2][1] = fmaxf(acc2[2][1], a2 + bv.y);
        acc2[2][2] = fmaxf(acc2[2][2], a2 + bv.z);
        acc2[2][3] = fmaxf(acc2[2][3], a2 + bv.w);
    }

    float* outp = sw + (size_t)bc * NN * NN;
    #pragma unroll
    for (int jx = 0; jx < 3; ++jx)
        #pragma unroll
        for (int jy = 0; jy < 4; ++jy)
            outp[(x0 + jx) * NN + y0 + jy] = __expf(acc2[jx][jy]) * w;
}

// ---------------------------------------------------------------------------
// Kernel 2: one thread per (b,x,y); all 16 triple outputs per thread.
// All sw reads coalesced (lanes consecutive in p); mask/out via int4/float4.
// ---------------------------------------------------------------------------
__global__ __launch_bounds__(256) void combine_kernel(
    const float* __restrict__ sw,      // [B,Nc,N,N]
    const int*   __restrict__ mask,    // [B,N,N,R]
    const float* __restrict__ biases,  // [R]
    float*       __restrict__ out)     // [B,N,N,R]
{
    const int idx = blockIdx.x * 256 + threadIdx.x;   // (b, p)
    if (idx >= BB * NN * NN) return;
    const int b = idx / (NN * NN);
    const int p = idx - b * (NN * NN);

    const float* base = sw + (size_t)b * NC * NN * NN + p;

    float acc[RR];
    #pragma unroll
    for (int t = 0; t < RR; ++t) {
        float s = biases[t];
        #pragma unroll
        for (int i = 0; i < NI; ++i)
            s += base[(size_t)(t * NI + i) * NN * NN];
        acc[t] = s;
    }

    const int4* m4 = (const int4*)(mask + (size_t)idx * RR);
    float4*     o4 = (float4*)(out + (size_t)idx * RR);
    #pragma unroll
    for (int q = 0; q < 4; ++q) {
        const int4 m = m4[q];
        float4 o;
        o.x = (m.x == 0) ? acc[q * 4 + 0] : -1000.0f;
        o.y = (m.y == 0) ? acc[q * 4 + 1] : -1000.0f;
        o.z = (m.z == 0) ? acc[q * 4 + 2] : -1000.0f;
        o.w = (m.w == 0) ? acc[q * 4 + 3] : -1000.0f;
        o4[q] = o;
    }
}

extern "C" void kernel_launch(void* const* d_in, const int* in_sizes, int n_in,
                              void* d_out, int out_size, void* d_ws, size_t ws_size,
                              hipStream_t stream)
{
    const float* trans   = (const float*)d_in[0];  // [B,N,N,T] f32
    const int*   mask    = (const int*)  d_in[1];  // [B,N,N,R] i32
    const int*   rules   = (const int*)  d_in[2];  // [Nc,3]    i32
    const float* weights = (const float*)d_in[3];  // [Nt,Ni]   f32
    const float* biases  = (const float*)d_in[4];  // [Nt]      f32
    float* out = (float*)d_out;
    float* sw  = (float*)d_ws;                     // [B,Nc,N,N] = 2.95 MB

    chain_dp_kernel<<<BB * NC, 192, 0, stream>>>(trans, rules, weights, sw);

    const int total = BB * NN * NN;                // one thread per (b,p)
    combine_kernel<<<(total + 255) / 256, 256, 0, stream>>>(sw, mask, biases, out);
}